// Round 5
// baseline (12535.706 us; speedup 1.0000x reference)
//
#include <hip/hip_runtime.h>
#include <hip/hip_bf16.h>
#include <stdint.h>

typedef unsigned short u16;
typedef unsigned long long u64;
typedef float f32x4 __attribute__((ext_vector_type(4)));
typedef short bf16x8 __attribute__((ext_vector_type(8)));

#define NB 32
#define NL 1024
#define ND 512
#define NH 512
#define G4 2048
#define NOUT 100
#define NFF 256
#define HSTR 536   // hs row stride (halfwords): 1072 B, 16B-aligned, odd/32 bank walk

__device__ inline u16 f2b(float f) {
    union { float f; unsigned i; } c; c.f = f;
    unsigned i = c.i;
    return (u16)((i + 0x7FFFu + ((i >> 16) & 1u)) >> 16);
}
__device__ inline bf16x8 cvt8(const float* __restrict__ p) {
    float4 a = *(const float4*)p;
    float4 b = *(const float4*)(p + 4);
    bf16x8 r;
    u16* h = (u16*)&r;
    h[0] = f2b(a.x); h[1] = f2b(a.y); h[2] = f2b(a.z); h[3] = f2b(a.w);
    h[4] = f2b(b.x); h[5] = f2b(b.y); h[6] = f2b(b.z); h[7] = f2b(b.w);
    return r;
}
__device__ inline f32x4 MF(bf16x8 a, bf16x8 b, f32x4 c) {
    return __builtin_amdgcn_mfma_f32_16x16x32_bf16(a, b, c, 0, 0, 0);
}
__device__ inline float tanh_f(float x) {
    float xx = fminf(fmaxf(x, -15.f), 15.f);
    float e = __expf(2.f * xx);
    return (e - 1.f) / (e + 1.f);
}
__device__ inline float sigm_f(float x) { return 1.f / (1.f + __expf(-x)); }

// cbias[b][r] = emb[concepts[b]] . Wih[r, 512:1024] + bih[r] + bhh[r]   (all fp32)
__global__ __launch_bounds__(256) void k_cbias(const float* __restrict__ emb,
                                               const int* __restrict__ concepts,
                                               const float* __restrict__ Wih,
                                               const float* __restrict__ bih,
                                               const float* __restrict__ bhh,
                                               float* __restrict__ cbias) {
    __shared__ float e[ND];
    int b = blockIdx.x;
    int r = blockIdx.y * 256 + threadIdx.x;
    int c = concepts[b];
    for (int i = threadIdx.x; i < ND; i += 256) e[i] = emb[c * ND + i];
    __syncthreads();
    const float* wrow = Wih + (size_t)r * 1024 + 512;
    float acc = 0.f;
#pragma unroll 4
    for (int k4 = 0; k4 < 128; k4++) {
        float4 wv = *(const float4*)&wrow[k4 * 4];
        acc += e[k4 * 4 + 0] * wv.x + e[k4 * 4 + 1] * wv.y +
               e[k4 * 4 + 2] * wv.z + e[k4 * 4 + 3] * wv.w;
    }
    cbias[b * G4 + r] = acc + bih[r] + bhh[r];
}

// Persistent LSTM: 32 blocks, block g owns h lanes [g*16, g*16+16) (64 gate rows).
// Weight fragments pinned in VGPRs via asm barrier (prevents per-step remat).
// Sync: per-block flag STORES (no RMW) + one coalesced 32-lane ballot poll.
__global__ __launch_bounds__(512, 1) void k_lstm(const float* __restrict__ x,
                                                 const float* __restrict__ Wih,
                                                 const float* __restrict__ Whh,
                                                 const float* __restrict__ cbias,
                                                 u16* __restrict__ out,
                                                 u64* __restrict__ h64,
                                                 int* __restrict__ flags) {
    __shared__ __align__(16) u16 hs[32 * HSTR];  // 33.5 KB
    __shared__ float gbuf[32 * 66];              // 8.4 KB
    __shared__ float cbuf[512];                  // 2 KB
    int g = blockIdx.x, tid = threadIdx.x;
    int w = tid >> 6, l = tid & 63, quad = l >> 4, lane = l & 15;
    int mt = w & 1, nt = w >> 1;
    int jj = g * 16;
    int rg = nt * NH + jj + lane;    // global gate row for this lane's B fragment
    int bA = mt * 16 + lane;         // batch row for A fragments

    // preload weight fragments ONCE (fp32 -> bf16), then pin in VGPRs
    bf16x8 wih_f[16], whh_f[16];
#pragma unroll
    for (int kk = 0; kk < 16; kk++) {
        wih_f[kk] = cvt8(&Wih[(size_t)rg * 1024 + kk * 32 + quad * 8]);
        whh_f[kk] = cvt8(&Whh[(size_t)rg * 512 + kk * 32 + quad * 8]);
    }
#pragma unroll
    for (int kk = 0; kk < 16; kk++)
        asm volatile("" : "+v"(wih_f[kk]), "+v"(whh_f[kk]));
    f32x4 cbv;
#pragma unroll
    for (int r = 0; r < 4; r++) cbv[r] = cbias[(size_t)(mt * 16 + quad * 4 + r) * G4 + rg];
    asm volatile("" : "+v"(cbv));
    cbuf[tid] = 0.f;
    __syncthreads();

    for (int t = 0; t < NL; t++) {
        // ---- x-part first (independent of h exchange; overlaps peers' stores)
        f32x4 acc = cbv;
        const float* xt = x + ((size_t)bA * NL + t) * ND;
#pragma unroll
        for (int kk = 0; kk < 16; kk++)
            acc = MF(cvt8(&xt[kk * 32 + quad * 8]), wih_f[kk], acc);

        if (t > 0) {
            if (tid < 64) {  // wave 0: coalesced poll of all 32 flags
                int slot = l & 31;
                for (;;) {
                    int v = __hip_atomic_load(&flags[slot], __ATOMIC_RELAXED,
                                              __HIP_MEMORY_SCOPE_AGENT);
                    if (__ballot(v < t) == 0ull) break;
                    __builtin_amdgcn_s_sleep(1);
                }
            }
            __syncthreads();   // (A)
            {   // stage h[t-1]: 32 rows x 128 u64; row=tid&31 for bank spread
                int row = tid & 31, c0 = tid >> 5;  // c0 in [0,16)
                const u64* src = h64 + (size_t)((t - 1) & 1) * 4096 + row * 128;
                char* dst = (char*)hs + row * (HSTR * 2);
#pragma unroll
                for (int i = 0; i < 8; i++) {
                    int col = c0 + i * 16;
                    u64 v = __hip_atomic_load(&src[col], __ATOMIC_RELAXED,
                                              __HIP_MEMORY_SCOPE_AGENT);
                    *(u64*)(dst + col * 8) = v;
                }
            }
            __syncthreads();   // (C)
#pragma unroll
            for (int kk = 0; kk < 16; kk++)
                acc = MF(*(bf16x8*)&hs[(mt * 16 + lane) * HSTR + kk * 32 + quad * 8],
                         whh_f[kk], acc);
        }
#pragma unroll
        for (int r = 0; r < 4; r++)
            gbuf[(mt * 16 + quad * 4 + r) * 66 + nt * 16 + lane] = acc[r];
        __syncthreads();       // (B)
        {   // cell: one (batch, j) per thread; pack 4 bf16 -> one relaxed atomic u64
            int bb = tid >> 4, j = tid & 15;
            float gi = gbuf[bb * 66 + j];
            float gf = gbuf[bb * 66 + 16 + j];
            float gg = gbuf[bb * 66 + 32 + j];
            float go = gbuf[bb * 66 + 48 + j];
            float iv = sigm_f(gi), fv = sigm_f(gf), ov = sigm_f(go);
            float gv = tanh_f(gg);
            float c = fv * cbuf[tid] + iv * gv;
            cbuf[tid] = c;
            u16 hb = f2b(ov * tanh_f(c));
            out[((size_t)bb * NL + t) * NH + jj + j] = hb;
            unsigned hb32 = (unsigned)hb;
            unsigned v1 = __shfl_down(hb32, 1);
            unsigned v2 = __shfl_down(hb32, 2);
            unsigned v3 = __shfl_down(hb32, 3);
            if ((j & 3) == 0) {
                u64 pk = (u64)hb32 | ((u64)v1 << 16) | ((u64)v2 << 32) | ((u64)v3 << 48);
                __hip_atomic_store(&h64[(size_t)(t & 1) * 4096 + bb * 128 + ((jj + j) >> 2)],
                                   pk, __ATOMIC_RELAXED, __HIP_MEMORY_SCOPE_AGENT);
            }
        }
        __syncthreads();       // (D) barrier drains all waves' vmcnt before announce
        if (tid == 0)
            __hip_atomic_store(&flags[g], t + 1, __ATOMIC_RELAXED, __HIP_MEMORY_SCOPE_AGENT);
    }
}

// Fused: Q = x@Wm^T+bm (prologue), flash attention with decayed-causal scores,
// FF head relu(W@W1^T+b1)@W2^T+b2 (epilogue). 16-row q tiles, 512 threads.
__global__ __launch_bounds__(512) void k_attn(const float* __restrict__ x,
                                              const float* __restrict__ Wm,
                                              const float* __restrict__ bm,
                                              const u16* __restrict__ kv,
                                              const float* __restrict__ W1,
                                              const float* __restrict__ b1,
                                              const float* __restrict__ W2,
                                              const float* __restrict__ b2,
                                              float* __restrict__ outp) {
    __shared__ __align__(16) u16 Qs[16 * 520];   // 16.6 KB (reused as H1)
    __shared__ __align__(16) u16 Vt[512 * 40];   // 40 KB   (reused as Wt)
    __shared__ float Sbuf[16 * 33];              // 2.1 KB
    __shared__ __align__(16) u16 Pbuf[16 * 40];  // 1.3 KB
    __shared__ float alpha_s[16];
    __shared__ float l_s[16];
    int b = blockIdx.x, qt = blockIdx.y;
    int tid = threadIdx.x, w = tid >> 6, l = tid & 63, quad = l >> 4, lane = l & 15;

    {   // prologue: Qs[16][512] = x_tile @ Wm^T + bm
        const float* xq = x + ((size_t)b * NL + qt * 16 + lane) * ND;
#pragma unroll
        for (int nt2 = 0; nt2 < 4; nt2++) {
            int n = (w * 4 + nt2) * 16 + lane;
            const float* wmp = Wm + (size_t)n * ND;
            f32x4 aq = {};
#pragma unroll 4
            for (int kk = 0; kk < 16; kk++)
                aq = MF(cvt8(&xq[kk * 32 + quad * 8]), cvt8(&wmp[kk * 32 + quad * 8]), aq);
            float bmv = bm[n];
#pragma unroll
            for (int r = 0; r < 4; r++)
                Qs[(quad * 4 + r) * 520 + n] = f2b(aq[r] + bmv);
        }
    }
    float m_run = -30000.f, l_run = 0.f;
    f32x4 acc[4] = {};
    __syncthreads();

    int st_max = ((qt << 4) + 15) >> 5;
    for (int st = 0; st <= st_max; st++) {
        if (w < 2) {  // QK^T: S[16][32], waves 0..1
            int ni = w;
            f32x4 s = {};
            const u16* krow = kv + ((size_t)b * NL + st * 32 + ni * 16 + lane) * NH;
#pragma unroll 4
            for (int kk = 0; kk < 16; kk++)
                s = MF(*(bf16x8*)&Qs[lane * 520 + kk * 32 + quad * 8],
                       *(const bf16x8*)&krow[kk * 32 + quad * 8], s);
            int scol = st * 32 + ni * 16 + lane;
#pragma unroll
            for (int r = 0; r < 4; r++) {
                int trow = (qt << 4) + quad * 4 + r;
                int dt = trow - scol;
                float v = (dt < 0) ? -30000.f : s[r] * __expf(-0.6f * (float)dt);
                Sbuf[(quad * 4 + r) * 33 + ni * 16 + lane] = v;
            }
        } else if (w >= 4) {  // stage V^T[512][32]
            int t2 = tid & 255;
            int srow = t2 >> 3, dseg = t2 & 7;
            const u16* vsrc = kv + ((size_t)b * NL + st * 32 + srow) * NH + dseg * 64;
#pragma unroll
            for (int i = 0; i < 8; i++) {
                union { uint4 v; u16 h[8]; } u;
                u.v = *(const uint4*)&vsrc[i * 8];
                int d0 = dseg * 64 + i * 8;
#pragma unroll
                for (int j2 = 0; j2 < 8; j2++) Vt[(d0 + j2) * 40 + srow] = u.h[j2];
            }
        }
        __syncthreads();
        if (tid < 16) {  // online softmax, one row per thread
            int m = tid;
            float vmax = -30000.f;
#pragma unroll 8
            for (int n = 0; n < 32; n++) vmax = fmaxf(vmax, Sbuf[m * 33 + n]);
            float mnew = fmaxf(m_run, vmax);
            float al = __expf(m_run - mnew);
            float lsum = 0.f;
#pragma unroll 8
            for (int n = 0; n < 32; n++) {
                float p = __expf(Sbuf[m * 33 + n] - mnew);
                lsum += p;
                Pbuf[m * 40 + n] = f2b(p);
            }
            l_run = l_run * al + lsum;
            m_run = mnew;
            alpha_s[m] = al;
            l_s[m] = l_run;
        }
        __syncthreads();
        {   // PV: each wave 4 dtiles (64 d-cols)
            float a0 = alpha_s[quad * 4 + 0];
            float a1 = alpha_s[quad * 4 + 1];
            float a2 = alpha_s[quad * 4 + 2];
            float a3 = alpha_s[quad * 4 + 3];
            bf16x8 afrag = *(bf16x8*)&Pbuf[lane * 40 + quad * 8];
#pragma unroll
            for (int di = 0; di < 4; di++) {
                int dtile = w * 4 + di;
                f32x4 c = acc[di];
                c[0] *= a0; c[1] *= a1; c[2] *= a2; c[3] *= a3;
                acc[di] = MF(afrag, *(bf16x8*)&Vt[(dtile * 16 + lane) * 40 + quad * 8], c);
            }
        }
        __syncthreads();
    }

    // ---- epilogue: weighted -> LDS (reuse Vt as bf16 [16][520]), then FF head
    u16* Wt = Vt;
    {
        float li0 = 1.f / l_s[quad * 4 + 0];
        float li1 = 1.f / l_s[quad * 4 + 1];
        float li2 = 1.f / l_s[quad * 4 + 2];
        float li3 = 1.f / l_s[quad * 4 + 3];
#pragma unroll
        for (int di = 0; di < 4; di++) {
            int col = (w * 4 + di) * 16 + lane;
            Wt[(quad * 4 + 0) * 520 + col] = f2b(acc[di][0] * li0);
            Wt[(quad * 4 + 1) * 520 + col] = f2b(acc[di][1] * li1);
            Wt[(quad * 4 + 2) * 520 + col] = f2b(acc[di][2] * li2);
            Wt[(quad * 4 + 3) * 520 + col] = f2b(acc[di][3] * li3);
        }
    }
    __syncthreads();
    u16* H1 = Qs;  // reuse
    {   // H1[16][256] = relu(Wt @ W1^T + b1)
#pragma unroll
        for (int nt2 = 0; nt2 < 2; nt2++) {
            int n = (w * 2 + nt2) * 16 + lane;
            const float* w1p = W1 + (size_t)n * ND;
            f32x4 a1 = {};
#pragma unroll 4
            for (int kk = 0; kk < 16; kk++)
                a1 = MF(*(bf16x8*)&Wt[lane * 520 + kk * 32 + quad * 8],
                        cvt8(&w1p[kk * 32 + quad * 8]), a1);
            float b1v = b1[n];
#pragma unroll
            for (int r = 0; r < 4; r++)
                H1[(quad * 4 + r) * 264 + n] = f2b(fmaxf(a1[r] + b1v, 0.f));
        }
    }
    __syncthreads();
    if (w < 7) {  // out[16][100] = H1 @ W2^T + b2   (fp32 store)
        int n = w * 16 + lane;
        int nc = n < NOUT ? n : NOUT - 1;
        const float* w2p = W2 + (size_t)nc * NFF;
        f32x4 a2 = {};
#pragma unroll
        for (int kk = 0; kk < 8; kk++)
            a2 = MF(*(bf16x8*)&H1[lane * 264 + kk * 32 + quad * 8],
                    cvt8(&w2p[kk * 32 + quad * 8]), a2);
        if (n < NOUT) {
            float b2v = b2[n];
#pragma unroll
            for (int r = 0; r < 4; r++)
                outp[((size_t)b * NL + (qt << 4) + quad * 4 + r) * NOUT + n] = a2[r] + b2v;
        }
    }
}

extern "C" void kernel_launch(void* const* d_in, const int* in_sizes, int n_in,
                              void* d_out, int out_size, void* d_ws, size_t ws_size,
                              hipStream_t stream) {
    const float* x        = (const float*)d_in[0];
    const int*   concepts = (const int*)d_in[1];
    const float* emb      = (const float*)d_in[2];
    const float* Wih      = (const float*)d_in[3];
    const float* Whh      = (const float*)d_in[4];
    const float* bih      = (const float*)d_in[5];
    const float* bhh      = (const float*)d_in[6];
    const float* Wm       = (const float*)d_in[7];
    const float* bm       = (const float*)d_in[8];
    const float* W1       = (const float*)d_in[9];
    const float* b1       = (const float*)d_in[10];
    const float* W2       = (const float*)d_in[11];
    const float* b2       = (const float*)d_in[12];
    float* outp = (float*)d_out;

    char* ws = (char*)d_ws;
    size_t off = 0;
    u16* lstm_out = (u16*)(ws + off); off += (size_t)NB * NL * NH * 2;  // 32 MB
    float* cbias  = (float*)(ws + off); off += (size_t)NB * G4 * 4;     // 256 KB
    u64* h64      = (u64*)(ws + off); off += (size_t)2 * 4096 * 8;      // 64 KB
    int* flags    = (int*)(ws + off); off += 128;

    hipMemsetAsync(flags, 0, 128, stream);
    k_cbias<<<dim3(NB, G4 / 256), 256, 0, stream>>>(emb, concepts, Wih, bih, bhh, cbias);
    k_lstm<<<32, 512, 0, stream>>>(x, Wih, Whh, cbias, lstm_out, h64, flags);
    k_attn<<<dim3(NB, NL / 16), 512, 0, stream>>>(x, Wm, bm, lstm_out, W1, b1, W2, b2, outp);
}

// Round 6
// 3335.262 us; speedup vs baseline: 3.7585x; 3.7585x over previous
//
#include <hip/hip_runtime.h>
#include <hip/hip_bf16.h>
#include <stdint.h>

typedef unsigned short u16;
typedef unsigned long long u64;
typedef float f32x4 __attribute__((ext_vector_type(4)));
typedef short bf16x8 __attribute__((ext_vector_type(8)));

#define NB 32
#define NL 1024
#define ND 512
#define NH 512
#define G4 2048
#define NOUT 100
#define NFF 256
#define HSTR 520   // LDS row stride in halfwords (1040 B, 16B-aligned, 2-way max)

__device__ inline u16 f2b(float f) {
    union { float f; unsigned i; } c; c.f = f;
    unsigned i = c.i;
    return (u16)((i + 0x7FFFu + ((i >> 16) & 1u)) >> 16);
}
__device__ inline bf16x8 cvt8(const float* __restrict__ p) {
    float4 a = *(const float4*)p;
    float4 b = *(const float4*)(p + 4);
    bf16x8 r;
    u16* h = (u16*)&r;
    h[0] = f2b(a.x); h[1] = f2b(a.y); h[2] = f2b(a.z); h[3] = f2b(a.w);
    h[4] = f2b(b.x); h[5] = f2b(b.y); h[6] = f2b(b.z); h[7] = f2b(b.w);
    return r;
}
__device__ inline f32x4 MF(bf16x8 a, bf16x8 b, f32x4 c) {
    return __builtin_amdgcn_mfma_f32_16x16x32_bf16(a, b, c, 0, 0, 0);
}
__device__ inline float tanh_f(float x) {
    float xx = fminf(fmaxf(x, -15.f), 15.f);
    float e = __expf(2.f * xx);
    return (e - 1.f) / (e + 1.f);
}
__device__ inline float sigm_f(float x) { return 1.f / (1.f + __expf(-x)); }

// cbias[b][r] = emb[concepts[b]] . Wih[r, 512:1024] + bih[r] + bhh[r]   (all fp32)
__global__ __launch_bounds__(256) void k_cbias(const float* __restrict__ emb,
                                               const int* __restrict__ concepts,
                                               const float* __restrict__ Wih,
                                               const float* __restrict__ bih,
                                               const float* __restrict__ bhh,
                                               float* __restrict__ cbias) {
    __shared__ float e[ND];
    int b = blockIdx.x;
    int r = blockIdx.y * 256 + threadIdx.x;
    int c = concepts[b];
    for (int i = threadIdx.x; i < ND; i += 256) e[i] = emb[c * ND + i];
    __syncthreads();
    const float* wrow = Wih + (size_t)r * 1024 + 512;
    float acc = 0.f;
#pragma unroll 4
    for (int k4 = 0; k4 < 128; k4++) {
        float4 wv = *(const float4*)&wrow[k4 * 4];
        acc += e[k4 * 4 + 0] * wv.x + e[k4 * 4 + 1] * wv.y +
               e[k4 * 4 + 2] * wv.z + e[k4 * 4 + 3] * wv.w;
    }
    cbias[b * G4 + r] = acc + bih[r] + bhh[r];
}

// Persistent LSTM, batch-split: 8 groups (XCD-swizzled) x 32 blocks.
// Group g owns batch rows [4g,4g+4); block k of a group owns h lanes [16k,16k+16)
// (64 gate rows). Weights in LDS (bf16); x double-buffer prefetched; per-step
// exchange = 4 KB of h via relaxed agent atomics + 64B-stride flags.
__global__ __launch_bounds__(256, 1) void k_lstm(const float* __restrict__ x,
                                                 const float* __restrict__ Wih,
                                                 const float* __restrict__ Whh,
                                                 const float* __restrict__ cbias,
                                                 u16* __restrict__ out,
                                                 u64* __restrict__ h64,
                                                 int* __restrict__ flags) {
    __shared__ __align__(16) u16 Wx[64 * HSTR];    // 66.6 KB  Wih x-part slice
    __shared__ __align__(16) u16 Wh[64 * HSTR];    // 66.6 KB  Whh slice
    __shared__ __align__(16) u16 hsb[4 * HSTR];    // 4.2 KB   h[t-1], 4 rows
    __shared__ __align__(16) u16 xb[2][4 * HSTR];  // 8.3 KB   x double buffer
    __shared__ float gbuf[4 * 68];                 // 1.1 KB
    __shared__ float cb_lds[4 * 64];               // 1.0 KB
    int g = blockIdx.x & 7, k = blockIdx.x >> 3;
    int tid = threadIdx.x;
    int w = tid >> 6, l = tid & 63, quad = l >> 4, lane = l & 15;
    int jj = k * 16;
    int b0 = g * 4;

    {   // ---- init: weight slices -> LDS (fp32 -> bf16), cbias slice, x[0]
        int row_loc = tid >> 2;            // 0..63: q*16+i
        int q = row_loc >> 4, i = row_loc & 15;
        int c0 = (tid & 3) * 128;
        const float* wsrc = Wih + (size_t)(q * 512 + jj + i) * 1024 + c0;  // x-part cols [0,512)
        const float* hsrc = Whh + (size_t)(q * 512 + jj + i) * 512 + c0;
#pragma unroll 4
        for (int j = 0; j < 16; j++) {
            *(bf16x8*)&Wx[row_loc * HSTR + c0 + j * 8] = cvt8(wsrc + j * 8);
            *(bf16x8*)&Wh[row_loc * HSTR + c0 + j * 8] = cvt8(hsrc + j * 8);
        }
        cb_lds[tid] = cbias[(size_t)(b0 + (tid >> 6)) * G4 +
                            (((tid >> 4) & 3) * 512) + jj + (tid & 15)];
        int rr = tid >> 6, f0 = (tid & 63) * 8;
        *(bf16x8*)&xb[0][rr * HSTR + f0] = cvt8(&x[((size_t)(b0 + rr) * NL) * ND + f0]);
    }
    __syncthreads();

    float c_reg = 0.f;                       // cell state (wave 0, lanes 0..63)
    u64* h64g = h64 + (size_t)g * 1024;      // per-group: 2 parity x 512 u64 (8 KB)
    int* flg = flags + g * 32 * 16;          // per-block flag, 64 B apart

    for (int t = 0; t < NL; t++) {
        // ---- prefetch x[t+1] (regs) — off critical path
        float4 pa, pb;
        int rr = tid >> 6, f0 = (tid & 63) * 8;
        if (t + 1 < NL) {
            const float* px = &x[((size_t)(b0 + rr) * NL + (t + 1)) * ND + f0];
            pa = *(const float4*)px; pb = *(const float4*)(px + 4);
        }
        // ---- x-part MFMA from xb[t&1] (wave w handles gate block q=w)
        f32x4 acc = {};
#pragma unroll
        for (int kk = 0; kk < 16; kk++) {
            bf16x8 a = *(bf16x8*)&xb[t & 1][(lane & 3) * HSTR + kk * 32 + quad * 8];
            bf16x8 bf = *(bf16x8*)&Wx[(w * 16 + lane) * HSTR + kk * 32 + quad * 8];
            acc = MF(a, bf, acc);
        }
        // ---- commit prefetched x to the other buffer
        if (t + 1 < NL) {
            bf16x8 xv; u16* hh = (u16*)&xv;
            hh[0] = f2b(pa.x); hh[1] = f2b(pa.y); hh[2] = f2b(pa.z); hh[3] = f2b(pa.w);
            hh[4] = f2b(pb.x); hh[5] = f2b(pb.y); hh[6] = f2b(pb.z); hh[7] = f2b(pb.w);
            *(bf16x8*)&xb[(t + 1) & 1][rr * HSTR + f0] = xv;
        }
        if (t > 0) {
            if (tid < 32) {   // coalesced-ish poll: one lane per producer flag
                for (;;) {
                    int v = __hip_atomic_load(&flg[tid * 16], __ATOMIC_RELAXED,
                                              __HIP_MEMORY_SCOPE_AGENT);
                    if (__ballot(v < t) == 0ull) break;
                    __builtin_amdgcn_s_sleep(2);
                }
            }
            __syncthreads();   // (A)
            {   // stage h[t-1]: 512 u64, 2 per thread, coalesced
                const u64* src = h64g + (size_t)((t - 1) & 1) * 512;
                u64 v0 = __hip_atomic_load(&src[tid], __ATOMIC_RELAXED,
                                           __HIP_MEMORY_SCOPE_AGENT);
                u64 v1 = __hip_atomic_load(&src[tid + 256], __ATOMIC_RELAXED,
                                           __HIP_MEMORY_SCOPE_AGENT);
                *(u64*)&hsb[(tid >> 7) * HSTR + (tid & 127) * 4] = v0;
                *(u64*)&hsb[((tid + 256) >> 7) * HSTR + ((tid + 256) & 127) * 4] = v1;
            }
            __syncthreads();   // (C)
#pragma unroll
            for (int kk = 0; kk < 16; kk++) {
                bf16x8 a = *(bf16x8*)&hsb[(lane & 3) * HSTR + kk * 32 + quad * 8];
                bf16x8 bf = *(bf16x8*)&Wh[(w * 16 + lane) * HSTR + kk * 32 + quad * 8];
                acc = MF(a, bf, acc);
            }
        }
        if (quad == 0) {   // C rows m=0..3 live in quad 0 regs
#pragma unroll
            for (int r = 0; r < 4; r++)
                gbuf[r * 68 + w * 16 + lane] = acc[r];
        }
        __syncthreads();   // (B)
        if (tid < 64) {    // cell: (row, j) per lane of wave 0
            int row = tid >> 4, j = tid & 15;
            float gi = gbuf[row * 68 + 0 * 16 + j] + cb_lds[row * 64 + 0 * 16 + j];
            float gf = gbuf[row * 68 + 1 * 16 + j] + cb_lds[row * 64 + 1 * 16 + j];
            float gg = gbuf[row * 68 + 2 * 16 + j] + cb_lds[row * 64 + 2 * 16 + j];
            float go = gbuf[row * 68 + 3 * 16 + j] + cb_lds[row * 64 + 3 * 16 + j];
            float iv = sigm_f(gi), fv = sigm_f(gf), ov = sigm_f(go);
            float gv = tanh_f(gg);
            c_reg = fv * c_reg + iv * gv;
            u16 hb = f2b(ov * tanh_f(c_reg));
            out[((size_t)(b0 + row) * NL + t) * NH + jj + j] = hb;
            unsigned hb32 = (unsigned)hb;
            unsigned v1 = __shfl_down(hb32, 1);
            unsigned v2 = __shfl_down(hb32, 2);
            unsigned v3 = __shfl_down(hb32, 3);
            if ((j & 3) == 0) {
                u64 pk = (u64)hb32 | ((u64)v1 << 16) | ((u64)v2 << 32) | ((u64)v3 << 48);
                __hip_atomic_store(&h64g[(size_t)(t & 1) * 512 + row * 128 + ((jj + j) >> 2)],
                                   pk, __ATOMIC_RELAXED, __HIP_MEMORY_SCOPE_AGENT);
            }
        }
        __syncthreads();   // (D) drains wave-0 h stores (vmcnt) before announce
        if (tid == 0)
            __hip_atomic_store(&flg[k * 16], t + 1, __ATOMIC_RELAXED,
                               __HIP_MEMORY_SCOPE_AGENT);
    }
}

// Fused: Q = x@Wm^T+bm (prologue), flash attention with decayed-causal scores,
// FF head relu(W@W1^T+b1)@W2^T+b2 (epilogue). 16-row q tiles, 512 threads.
__global__ __launch_bounds__(512) void k_attn(const float* __restrict__ x,
                                              const float* __restrict__ Wm,
                                              const float* __restrict__ bm,
                                              const u16* __restrict__ kv,
                                              const float* __restrict__ W1,
                                              const float* __restrict__ b1,
                                              const float* __restrict__ W2,
                                              const float* __restrict__ b2,
                                              float* __restrict__ outp) {
    __shared__ __align__(16) u16 Qs[16 * 520];
    __shared__ __align__(16) u16 Vt[512 * 40];
    __shared__ float Sbuf[16 * 33];
    __shared__ __align__(16) u16 Pbuf[16 * 40];
    __shared__ float alpha_s[16];
    __shared__ float l_s[16];
    int b = blockIdx.x, qt = blockIdx.y;
    int tid = threadIdx.x, w = tid >> 6, l = tid & 63, quad = l >> 4, lane = l & 15;

    {   // prologue: Qs[16][512] = x_tile @ Wm^T + bm
        const float* xq = x + ((size_t)b * NL + qt * 16 + lane) * ND;
#pragma unroll
        for (int nt2 = 0; nt2 < 4; nt2++) {
            int n = (w * 4 + nt2) * 16 + lane;
            const float* wmp = Wm + (size_t)n * ND;
            f32x4 aq = {};
#pragma unroll 4
            for (int kk = 0; kk < 16; kk++)
                aq = MF(cvt8(&xq[kk * 32 + quad * 8]), cvt8(&wmp[kk * 32 + quad * 8]), aq);
            float bmv = bm[n];
#pragma unroll
            for (int r = 0; r < 4; r++)
                Qs[(quad * 4 + r) * 520 + n] = f2b(aq[r] + bmv);
        }
    }
    float m_run = -30000.f, l_run = 0.f;
    f32x4 acc[4] = {};
    __syncthreads();

    int st_max = ((qt << 4) + 15) >> 5;
    for (int st = 0; st <= st_max; st++) {
        if (w < 2) {  // QK^T: S[16][32], waves 0..1
            int ni = w;
            f32x4 s = {};
            const u16* krow = kv + ((size_t)b * NL + st * 32 + ni * 16 + lane) * NH;
#pragma unroll 4
            for (int kk = 0; kk < 16; kk++)
                s = MF(*(bf16x8*)&Qs[lane * 520 + kk * 32 + quad * 8],
                       *(const bf16x8*)&krow[kk * 32 + quad * 8], s);
            int scol = st * 32 + ni * 16 + lane;
#pragma unroll
            for (int r = 0; r < 4; r++) {
                int trow = (qt << 4) + quad * 4 + r;
                int dt = trow - scol;
                float v = (dt < 0) ? -30000.f : s[r] * __expf(-0.6f * (float)dt);
                Sbuf[(quad * 4 + r) * 33 + ni * 16 + lane] = v;
            }
        } else if (w >= 4) {  // stage V^T[512][32]
            int t2 = tid & 255;
            int srow = t2 >> 3, dseg = t2 & 7;
            const u16* vsrc = kv + ((size_t)b * NL + st * 32 + srow) * NH + dseg * 64;
#pragma unroll
            for (int i = 0; i < 8; i++) {
                union { uint4 v; u16 h[8]; } u;
                u.v = *(const uint4*)&vsrc[i * 8];
                int d0 = dseg * 64 + i * 8;
#pragma unroll
                for (int j2 = 0; j2 < 8; j2++) Vt[(d0 + j2) * 40 + srow] = u.h[j2];
            }
        }
        __syncthreads();
        if (tid < 16) {  // online softmax
            int m = tid;
            float vmax = -30000.f;
#pragma unroll 8
            for (int n = 0; n < 32; n++) vmax = fmaxf(vmax, Sbuf[m * 33 + n]);
            float mnew = fmaxf(m_run, vmax);
            float al = __expf(m_run - mnew);
            float lsum = 0.f;
#pragma unroll 8
            for (int n = 0; n < 32; n++) {
                float p = __expf(Sbuf[m * 33 + n] - mnew);
                lsum += p;
                Pbuf[m * 40 + n] = f2b(p);
            }
            l_run = l_run * al + lsum;
            m_run = mnew;
            alpha_s[m] = al;
            l_s[m] = l_run;
        }
        __syncthreads();
        {   // PV
            float a0 = alpha_s[quad * 4 + 0];
            float a1 = alpha_s[quad * 4 + 1];
            float a2 = alpha_s[quad * 4 + 2];
            float a3 = alpha_s[quad * 4 + 3];
            bf16x8 afrag = *(bf16x8*)&Pbuf[lane * 40 + quad * 8];
#pragma unroll
            for (int di = 0; di < 4; di++) {
                int dtile = w * 4 + di;
                f32x4 c = acc[di];
                c[0] *= a0; c[1] *= a1; c[2] *= a2; c[3] *= a3;
                acc[di] = MF(afrag, *(bf16x8*)&Vt[(dtile * 16 + lane) * 40 + quad * 8], c);
            }
        }
        __syncthreads();
    }

    u16* Wt = Vt;   // weighted -> LDS
    {
        float li0 = 1.f / l_s[quad * 4 + 0];
        float li1 = 1.f / l_s[quad * 4 + 1];
        float li2 = 1.f / l_s[quad * 4 + 2];
        float li3 = 1.f / l_s[quad * 4 + 3];
#pragma unroll
        for (int di = 0; di < 4; di++) {
            int col = (w * 4 + di) * 16 + lane;
            Wt[(quad * 4 + 0) * 520 + col] = f2b(acc[di][0] * li0);
            Wt[(quad * 4 + 1) * 520 + col] = f2b(acc[di][1] * li1);
            Wt[(quad * 4 + 2) * 520 + col] = f2b(acc[di][2] * li2);
            Wt[(quad * 4 + 3) * 520 + col] = f2b(acc[di][3] * li3);
        }
    }
    __syncthreads();
    u16* H1 = Qs;
    {   // H1[16][256] = relu(Wt @ W1^T + b1)
#pragma unroll
        for (int nt2 = 0; nt2 < 2; nt2++) {
            int n = (w * 2 + nt2) * 16 + lane;
            const float* w1p = W1 + (size_t)n * ND;
            f32x4 a1 = {};
#pragma unroll 4
            for (int kk = 0; kk < 16; kk++)
                a1 = MF(*(bf16x8*)&Wt[lane * 520 + kk * 32 + quad * 8],
                        cvt8(&w1p[kk * 32 + quad * 8]), a1);
            float b1v = b1[n];
#pragma unroll
            for (int r = 0; r < 4; r++)
                H1[(quad * 4 + r) * 264 + n] = f2b(fmaxf(a1[r] + b1v, 0.f));
        }
    }
    __syncthreads();
    if (w < 7) {  // out[16][100] = H1 @ W2^T + b2
        int n = w * 16 + lane;
        int nc = n < NOUT ? n : NOUT - 1;
        const float* w2p = W2 + (size_t)nc * NFF;
        f32x4 a2 = {};
#pragma unroll
        for (int kk = 0; kk < 8; kk++)
            a2 = MF(*(bf16x8*)&H1[lane * 264 + kk * 32 + quad * 8],
                    cvt8(&w2p[kk * 32 + quad * 8]), a2);
        if (n < NOUT) {
            float b2v = b2[n];
#pragma unroll
            for (int r = 0; r < 4; r++)
                outp[((size_t)b * NL + (qt << 4) + quad * 4 + r) * NOUT + n] = a2[r] + b2v;
        }
    }
}

extern "C" void kernel_launch(void* const* d_in, const int* in_sizes, int n_in,
                              void* d_out, int out_size, void* d_ws, size_t ws_size,
                              hipStream_t stream) {
    const float* x        = (const float*)d_in[0];
    const int*   concepts = (const int*)d_in[1];
    const float* emb      = (const float*)d_in[2];
    const float* Wih      = (const float*)d_in[3];
    const float* Whh      = (const float*)d_in[4];
    const float* bih      = (const float*)d_in[5];
    const float* bhh      = (const float*)d_in[6];
    const float* Wm       = (const float*)d_in[7];
    const float* bm       = (const float*)d_in[8];
    const float* W1       = (const float*)d_in[9];
    const float* b1       = (const float*)d_in[10];
    const float* W2       = (const float*)d_in[11];
    const float* b2       = (const float*)d_in[12];
    float* outp = (float*)d_out;

    char* ws = (char*)d_ws;
    size_t off = 0;
    u16* lstm_out = (u16*)(ws + off); off += (size_t)NB * NL * NH * 2;   // 32 MB
    float* cbias  = (float*)(ws + off); off += (size_t)NB * G4 * 4;      // 256 KB
    u64* h64      = (u64*)(ws + off); off += (size_t)8 * 1024 * 8;       // 64 KB
    int* flags    = (int*)(ws + off); off += 8 * 32 * 16 * 4;            // 16 KB

    hipMemsetAsync(flags, 0, 8 * 32 * 16 * 4, stream);
    k_cbias<<<dim3(NB, G4 / 256), 256, 0, stream>>>(emb, concepts, Wih, bih, bhh, cbias);
    k_lstm<<<256, 256, 0, stream>>>(x, Wih, Whh, cbias, lstm_out, h64, flags);
    k_attn<<<dim3(NB, NL / 16), 512, 0, stream>>>(x, Wm, bm, lstm_out, W1, b1, W2, b2, outp);
}

// Round 7
// 3302.372 us; speedup vs baseline: 3.7960x; 1.0100x over previous
//
#include <hip/hip_runtime.h>
#include <hip/hip_bf16.h>
#include <stdint.h>

typedef unsigned short u16;
typedef unsigned long long u64;
typedef float f32x4 __attribute__((ext_vector_type(4)));
typedef short bf16x8 __attribute__((ext_vector_type(8)));

#define NB 32
#define NL 1024
#define ND 512
#define NH 512
#define G4 2048
#define NOUT 100
#define NFF 256
#define HSTR 520   // LDS row stride (halfwords) for hsb/xb

__device__ inline u16 f2b(float f) {
    union { float f; unsigned i; } c; c.f = f;
    unsigned i = c.i;
    return (u16)((i + 0x7FFFu + ((i >> 16) & 1u)) >> 16);
}
__device__ inline bf16x8 cvt8(const float* __restrict__ p) {
    float4 a = *(const float4*)p;
    float4 b = *(const float4*)(p + 4);
    bf16x8 r;
    u16* h = (u16*)&r;
    h[0] = f2b(a.x); h[1] = f2b(a.y); h[2] = f2b(a.z); h[3] = f2b(a.w);
    h[4] = f2b(b.x); h[5] = f2b(b.y); h[6] = f2b(b.z); h[7] = f2b(b.w);
    return r;
}
__device__ inline f32x4 MF(bf16x8 a, bf16x8 b, f32x4 c) {
    return __builtin_amdgcn_mfma_f32_16x16x32_bf16(a, b, c, 0, 0, 0);
}
__device__ inline float tanh_f(float x) {
    float xx = fminf(fmaxf(x, -15.f), 15.f);
    float e = __expf(2.f * xx);
    return (e - 1.f) / (e + 1.f);
}
__device__ inline float sigm_f(float x) { return 1.f / (1.f + __expf(-x)); }

// cbias[b][r] = emb[concepts[b]] . Wih[r, 512:1024] + bih[r] + bhh[r]   (all fp32)
__global__ __launch_bounds__(256) void k_cbias(const float* __restrict__ emb,
                                               const int* __restrict__ concepts,
                                               const float* __restrict__ Wih,
                                               const float* __restrict__ bih,
                                               const float* __restrict__ bhh,
                                               float* __restrict__ cbias) {
    __shared__ float e[ND];
    int b = blockIdx.x;
    int r = blockIdx.y * 256 + threadIdx.x;
    int c = concepts[b];
    for (int i = threadIdx.x; i < ND; i += 256) e[i] = emb[c * ND + i];
    __syncthreads();
    const float* wrow = Wih + (size_t)r * 1024 + 512;
    float acc = 0.f;
#pragma unroll 4
    for (int k4 = 0; k4 < 128; k4++) {
        float4 wv = *(const float4*)&wrow[k4 * 4];
        acc += e[k4 * 4 + 0] * wv.x + e[k4 * 4 + 1] * wv.y +
               e[k4 * 4 + 2] * wv.z + e[k4 * 4 + 3] * wv.w;
    }
    cbias[b * G4 + r] = acc + bih[r] + bhh[r];
}

// Persistent LSTM, batch-split: 8 groups (one XCD each via blockIdx&7) x 32 blocks.
// Group g owns batch rows [4g,4g+4); block k owns h lanes [16k,16k+16) (64 gate rows).
// Weights in LDS in FRAGMENT-MAJOR order: WxS[((w*16+kk)*64+l)*8] so each wave's
// B-fragment ds_read_b128 burst is contiguous 1 KB -> conflict-free.
// No end-of-step barrier: wave 0 orders h-store->flag with in-wave vmcnt(0).
__global__ __launch_bounds__(256, 1) void k_lstm(const float* __restrict__ x,
                                                 const float* __restrict__ Wih,
                                                 const float* __restrict__ Whh,
                                                 const float* __restrict__ cbias,
                                                 u16* __restrict__ out,
                                                 u64* __restrict__ h64,
                                                 int* __restrict__ flags) {
    __shared__ __align__(16) u16 WxS[4 * 16 * 64 * 8];  // 64 KB, fragment-major
    __shared__ __align__(16) u16 WhS[4 * 16 * 64 * 8];  // 64 KB
    __shared__ __align__(16) u16 hsb[4 * HSTR];         // 4.2 KB
    __shared__ __align__(16) u16 xb[2][4 * HSTR];       // 8.3 KB
    __shared__ float gbuf[4 * 68];                      // 1.1 KB
    __shared__ float cb_lds[4 * 64];                    // 1.0 KB
    int g = blockIdx.x & 7, k = blockIdx.x >> 3;
    int tid = threadIdx.x;
    int w = tid >> 6, l = tid & 63, quad = l >> 4, lane = l & 15;
    int jj = k * 16;
    int b0 = g * 4;

    {   // ---- init: weights -> LDS fragment-major (fp32->bf16), cbias, x[0]
        int n = l & 15, q4 = l >> 4;
        const float* wsrc = Wih + (size_t)(w * 512 + jj + n) * 1024 + q4 * 8;  // x-part
        const float* hsrc = Whh + (size_t)(w * 512 + jj + n) * 512 + q4 * 8;
#pragma unroll 4
        for (int kk = 0; kk < 16; kk++) {
            int dst = ((w * 16 + kk) * 64 + l) * 8;
            *(bf16x8*)&WxS[dst] = cvt8(wsrc + kk * 32);
            *(bf16x8*)&WhS[dst] = cvt8(hsrc + kk * 32);
        }
        cb_lds[tid] = cbias[(size_t)(b0 + (tid >> 6)) * G4 +
                            (((tid >> 4) & 3) * 512) + jj + (tid & 15)];
        int rr = tid >> 6, f0 = (tid & 63) * 8;
        *(bf16x8*)&xb[0][rr * HSTR + f0] = cvt8(&x[((size_t)(b0 + rr) * NL) * ND + f0]);
    }
    __syncthreads();

    float c_reg = 0.f;                       // cell state (wave 0 lanes)
    u64* h64g = h64 + (size_t)g * 1024;      // per-group: 2 parity x 512 u64
    int* flg = flags + g * 32 * 16;          // per-block flag, 64 B apart

    for (int t = 0; t < NL; t++) {
        // ---- prefetch x[t+1] (regs) — off critical path
        float4 pa, pb;
        int rr = tid >> 6, f0 = (tid & 63) * 8;
        if (t + 1 < NL) {
            const float* px = &x[((size_t)(b0 + rr) * NL + (t + 1)) * ND + f0];
            pa = *(const float4*)px; pb = *(const float4*)(px + 4);
        }
        // ---- x-part MFMA (wave w = gate block q)
        f32x4 acc = {};
#pragma unroll
        for (int kk = 0; kk < 16; kk++) {
            bf16x8 a = *(bf16x8*)&xb[t & 1][(lane & 3) * HSTR + kk * 32 + quad * 8];
            bf16x8 bf = *(bf16x8*)&WxS[((w * 16 + kk) * 64 + l) * 8];
            acc = MF(a, bf, acc);
        }
        // ---- commit prefetched x
        if (t + 1 < NL) {
            bf16x8 xv; u16* hh = (u16*)&xv;
            hh[0] = f2b(pa.x); hh[1] = f2b(pa.y); hh[2] = f2b(pa.z); hh[3] = f2b(pa.w);
            hh[4] = f2b(pb.x); hh[5] = f2b(pb.y); hh[6] = f2b(pb.z); hh[7] = f2b(pb.w);
            *(bf16x8*)&xb[(t + 1) & 1][rr * HSTR + f0] = xv;
        }
        if (t > 0) {
            if (tid < 32) {   // wave 0: one lane per producer flag
                for (;;) {
                    int v = __hip_atomic_load(&flg[tid * 16], __ATOMIC_RELAXED,
                                              __HIP_MEMORY_SCOPE_AGENT);
                    if (__ballot(v < t) == 0ull) break;
                    __builtin_amdgcn_s_sleep(2);
                }
            }
            __syncthreads();   // (A)
            {   // stage h[t-1]: 512 u64, 2 per thread, coalesced
                const u64* src = h64g + (size_t)((t - 1) & 1) * 512;
                u64 v0 = __hip_atomic_load(&src[tid], __ATOMIC_RELAXED,
                                           __HIP_MEMORY_SCOPE_AGENT);
                u64 v1 = __hip_atomic_load(&src[tid + 256], __ATOMIC_RELAXED,
                                           __HIP_MEMORY_SCOPE_AGENT);
                *(u64*)&hsb[(tid >> 7) * HSTR + (tid & 127) * 4] = v0;
                *(u64*)&hsb[((tid + 256) >> 7) * HSTR + ((tid + 256) & 127) * 4] = v1;
            }
            __syncthreads();   // (C)
#pragma unroll
            for (int kk = 0; kk < 16; kk++) {
                bf16x8 a = *(bf16x8*)&hsb[(lane & 3) * HSTR + kk * 32 + quad * 8];
                bf16x8 bf = *(bf16x8*)&WhS[((w * 16 + kk) * 64 + l) * 8];
                acc = MF(a, bf, acc);
            }
        }
        if (quad == 0) {   // C rows m=0..3 live in quad 0 regs
#pragma unroll
            for (int r = 0; r < 4; r++)
                gbuf[r * 68 + w * 16 + lane] = acc[r];
        }
        __syncthreads();   // (B)
        if (tid < 64) {    // cell (wave 0 only); no trailing block barrier
            int row = tid >> 4, j = tid & 15;
            float gi = gbuf[row * 68 + 0 * 16 + j] + cb_lds[row * 64 + 0 * 16 + j];
            float gf = gbuf[row * 68 + 1 * 16 + j] + cb_lds[row * 64 + 1 * 16 + j];
            float gg = gbuf[row * 68 + 2 * 16 + j] + cb_lds[row * 64 + 2 * 16 + j];
            float go = gbuf[row * 68 + 3 * 16 + j] + cb_lds[row * 64 + 3 * 16 + j];
            float iv = sigm_f(gi), fv = sigm_f(gf), ov = sigm_f(go);
            float gv = tanh_f(gg);
            c_reg = fv * c_reg + iv * gv;
            u16 hb = f2b(ov * tanh_f(c_reg));
            unsigned hb32 = (unsigned)hb;
            unsigned v1 = __shfl_down(hb32, 1);
            unsigned v2 = __shfl_down(hb32, 2);
            unsigned v3 = __shfl_down(hb32, 3);
            u64 pk = (u64)hb32 | ((u64)v1 << 16) | ((u64)v2 << 32) | ((u64)v3 << 48);
            if ((j & 3) == 0)
                __hip_atomic_store(&h64g[(size_t)(t & 1) * 512 + row * 128 + ((jj + j) >> 2)],
                                   pk, __ATOMIC_RELAXED, __HIP_MEMORY_SCOPE_AGENT);
            asm volatile("s_waitcnt vmcnt(0)" ::: "memory");  // drain h stores (wave-local)
            if (tid == 0)
                __hip_atomic_store(&flg[k * 16], t + 1, __ATOMIC_RELAXED,
                                   __HIP_MEMORY_SCOPE_AGENT);
            if ((j & 3) == 0)   // lstm_out write off the sync path
                *(u64*)&out[((size_t)(b0 + row) * NL + t) * NH + jj + j] = pk;
        }
    }
}

// Fused: Q = x@Wm^T+bm (prologue), flash attention with decayed-causal scores,
// FF head relu(W@W1^T+b1)@W2^T+b2 (epilogue). 16-row q tiles, 512 threads.
__global__ __launch_bounds__(512) void k_attn(const float* __restrict__ x,
                                              const float* __restrict__ Wm,
                                              const float* __restrict__ bm,
                                              const u16* __restrict__ kv,
                                              const float* __restrict__ W1,
                                              const float* __restrict__ b1,
                                              const float* __restrict__ W2,
                                              const float* __restrict__ b2,
                                              float* __restrict__ outp) {
    __shared__ __align__(16) u16 Qs[16 * 520];
    __shared__ __align__(16) u16 Vt[512 * 40];
    __shared__ float Sbuf[16 * 33];
    __shared__ __align__(16) u16 Pbuf[16 * 40];
    __shared__ float alpha_s[16];
    __shared__ float l_s[16];
    int b = blockIdx.x, qt = blockIdx.y;
    int tid = threadIdx.x, w = tid >> 6, l = tid & 63, quad = l >> 4, lane = l & 15;

    {   // prologue: Qs[16][512] = x_tile @ Wm^T + bm
        const float* xq = x + ((size_t)b * NL + qt * 16 + lane) * ND;
#pragma unroll
        for (int nt2 = 0; nt2 < 4; nt2++) {
            int n = (w * 4 + nt2) * 16 + lane;
            const float* wmp = Wm + (size_t)n * ND;
            f32x4 aq = {};
#pragma unroll 4
            for (int kk = 0; kk < 16; kk++)
                aq = MF(cvt8(&xq[kk * 32 + quad * 8]), cvt8(&wmp[kk * 32 + quad * 8]), aq);
            float bmv = bm[n];
#pragma unroll
            for (int r = 0; r < 4; r++)
                Qs[(quad * 4 + r) * 520 + n] = f2b(aq[r] + bmv);
        }
    }
    float m_run = -30000.f, l_run = 0.f;
    f32x4 acc[4] = {};
    __syncthreads();

    int st_max = ((qt << 4) + 15) >> 5;
    for (int st = 0; st <= st_max; st++) {
        if (w < 2) {  // QK^T: S[16][32], waves 0..1
            int ni = w;
            f32x4 s = {};
            const u16* krow = kv + ((size_t)b * NL + st * 32 + ni * 16 + lane) * NH;
#pragma unroll 4
            for (int kk = 0; kk < 16; kk++)
                s = MF(*(bf16x8*)&Qs[lane * 520 + kk * 32 + quad * 8],
                       *(const bf16x8*)&krow[kk * 32 + quad * 8], s);
            int scol = st * 32 + ni * 16 + lane;
#pragma unroll
            for (int r = 0; r < 4; r++) {
                int trow = (qt << 4) + quad * 4 + r;
                int dt = trow - scol;
                float v = (dt < 0) ? -30000.f : s[r] * __expf(-0.6f * (float)dt);
                Sbuf[(quad * 4 + r) * 33 + ni * 16 + lane] = v;
            }
        } else if (w >= 4) {  // stage V^T[512][32]
            int t2 = tid & 255;
            int srow = t2 >> 3, dseg = t2 & 7;
            const u16* vsrc = kv + ((size_t)b * NL + st * 32 + srow) * NH + dseg * 64;
#pragma unroll
            for (int i = 0; i < 8; i++) {
                union { uint4 v; u16 h[8]; } u;
                u.v = *(const uint4*)&vsrc[i * 8];
                int d0 = dseg * 64 + i * 8;
#pragma unroll
                for (int j2 = 0; j2 < 8; j2++) Vt[(d0 + j2) * 40 + srow] = u.h[j2];
            }
        }
        __syncthreads();
        if (tid < 16) {  // online softmax
            int m = tid;
            float vmax = -30000.f;
#pragma unroll 8
            for (int n = 0; n < 32; n++) vmax = fmaxf(vmax, Sbuf[m * 33 + n]);
            float mnew = fmaxf(m_run, vmax);
            float al = __expf(m_run - mnew);
            float lsum = 0.f;
#pragma unroll 8
            for (int n = 0; n < 32; n++) {
                float p = __expf(Sbuf[m * 33 + n] - mnew);
                lsum += p;
                Pbuf[m * 40 + n] = f2b(p);
            }
            l_run = l_run * al + lsum;
            m_run = mnew;
            alpha_s[m] = al;
            l_s[m] = l_run;
        }
        __syncthreads();
        {   // PV
            float a0 = alpha_s[quad * 4 + 0];
            float a1 = alpha_s[quad * 4 + 1];
            float a2 = alpha_s[quad * 4 + 2];
            float a3 = alpha_s[quad * 4 + 3];
            bf16x8 afrag = *(bf16x8*)&Pbuf[lane * 40 + quad * 8];
#pragma unroll
            for (int di = 0; di < 4; di++) {
                int dtile = w * 4 + di;
                f32x4 c = acc[di];
                c[0] *= a0; c[1] *= a1; c[2] *= a2; c[3] *= a3;
                acc[di] = MF(afrag, *(bf16x8*)&Vt[(dtile * 16 + lane) * 40 + quad * 8], c);
            }
        }
        __syncthreads();
    }

    u16* Wt = Vt;   // weighted -> LDS
    {
        float li0 = 1.f / l_s[quad * 4 + 0];
        float li1 = 1.f / l_s[quad * 4 + 1];
        float li2 = 1.f / l_s[quad * 4 + 2];
        float li3 = 1.f / l_s[quad * 4 + 3];
#pragma unroll
        for (int di = 0; di < 4; di++) {
            int col = (w * 4 + di) * 16 + lane;
            Wt[(quad * 4 + 0) * 520 + col] = f2b(acc[di][0] * li0);
            Wt[(quad * 4 + 1) * 520 + col] = f2b(acc[di][1] * li1);
            Wt[(quad * 4 + 2) * 520 + col] = f2b(acc[di][2] * li2);
            Wt[(quad * 4 + 3) * 520 + col] = f2b(acc[di][3] * li3);
        }
    }
    __syncthreads();
    u16* H1 = Qs;
    {   // H1[16][256] = relu(Wt @ W1^T + b1)
#pragma unroll
        for (int nt2 = 0; nt2 < 2; nt2++) {
            int n = (w * 2 + nt2) * 16 + lane;
            const float* w1p = W1 + (size_t)n * ND;
            f32x4 a1 = {};
#pragma unroll 4
            for (int kk = 0; kk < 16; kk++)
                a1 = MF(*(bf16x8*)&Wt[lane * 520 + kk * 32 + quad * 8],
                        cvt8(&w1p[kk * 32 + quad * 8]), a1);
            float b1v = b1[n];
#pragma unroll
            for (int r = 0; r < 4; r++)
                H1[(quad * 4 + r) * 264 + n] = f2b(fmaxf(a1[r] + b1v, 0.f));
        }
    }
    __syncthreads();
    if (w < 7) {  // out[16][100] = H1 @ W2^T + b2
        int n = w * 16 + lane;
        int nc = n < NOUT ? n : NOUT - 1;
        const float* w2p = W2 + (size_t)nc * NFF;
        f32x4 a2 = {};
#pragma unroll
        for (int kk = 0; kk < 8; kk++)
            a2 = MF(*(bf16x8*)&H1[lane * 264 + kk * 32 + quad * 8],
                    cvt8(&w2p[kk * 32 + quad * 8]), a2);
        if (n < NOUT) {
            float b2v = b2[n];
#pragma unroll
            for (int r = 0; r < 4; r++)
                outp[((size_t)b * NL + (qt << 4) + quad * 4 + r) * NOUT + n] = a2[r] + b2v;
        }
    }
}

extern "C" void kernel_launch(void* const* d_in, const int* in_sizes, int n_in,
                              void* d_out, int out_size, void* d_ws, size_t ws_size,
                              hipStream_t stream) {
    const float* x        = (const float*)d_in[0];
    const int*   concepts = (const int*)d_in[1];
    const float* emb      = (const float*)d_in[2];
    const float* Wih      = (const float*)d_in[3];
    const float* Whh      = (const float*)d_in[4];
    const float* bih      = (const float*)d_in[5];
    const float* bhh      = (const float*)d_in[6];
    const float* Wm       = (const float*)d_in[7];
    const float* bm       = (const float*)d_in[8];
    const float* W1       = (const float*)d_in[9];
    const float* b1       = (const float*)d_in[10];
    const float* W2       = (const float*)d_in[11];
    const float* b2       = (const float*)d_in[12];
    float* outp = (float*)d_out;

    char* ws = (char*)d_ws;
    size_t off = 0;
    u16* lstm_out = (u16*)(ws + off); off += (size_t)NB * NL * NH * 2;   // 32 MB
    float* cbias  = (float*)(ws + off); off += (size_t)NB * G4 * 4;      // 256 KB
    u64* h64      = (u64*)(ws + off); off += (size_t)8 * 1024 * 8;       // 64 KB
    int* flags    = (int*)(ws + off); off += 8 * 32 * 16 * 4;            // 16 KB

    hipMemsetAsync(flags, 0, 8 * 32 * 16 * 4, stream);
    k_cbias<<<dim3(NB, G4 / 256), 256, 0, stream>>>(emb, concepts, Wih, bih, bhh, cbias);
    k_lstm<<<256, 256, 0, stream>>>(x, Wih, Whh, cbias, lstm_out, h64, flags);
    k_attn<<<dim3(NB, NL / 16), 512, 0, stream>>>(x, Wm, bm, lstm_out, W1, b1, W2, b2, outp);
}